// Round 6
// baseline (3379.635 us; speedup 1.0000x reference)
//
#include <hip/hip_runtime.h>

typedef __attribute__((ext_vector_type(8))) _Float16 f16x8;
typedef __attribute__((ext_vector_type(4))) float    f32x4;

#define HD    256
#define CIN   16
#define TIN   48
#define TOUT  24
#define COUT  8
#define MB    16            // batch rows per block -> 2 blocks/CU co-resident
#define KPAD  296           // padded row stride (halves) for hF
#define KT_ENC 9            // K = 288 (h 256 | x 16 | pad 16)
#define KT_DEC 8            // K = 256
#define WE_HALVES (KT_ENC*4*16*512)   // 294912
#define WD_HALVES (KT_DEC*4*16*512)   // 262144
#define PREP_TOTAL (WE_HALVES + WD_HALVES)

template <int N> struct KTag { static constexpr int val = N; };

// Fragment-major fp16 weights: frag id = kt*64 + g*16 + ntile, each frag is
// 64 lanes x 8 halves with b_frag[lane][s] = W[k = kt*32 + (lane>>4)*8 + s]
//                                             [col = g*256 + ntile*16 + (lane&15)]
__global__ void prep_frags(const float* __restrict__ enc_Wih,
                           const float* __restrict__ enc_Whh,
                           const float* __restrict__ dec_Whh,
                           _Float16* __restrict__ wf)
{
    int p = blockIdx.x * blockDim.x + threadIdx.x;
    if (p >= PREP_TOTAL) return;
    int lane = (p >> 3) & 63;
    int s    = p & 7;
    int kq   = ((lane >> 4) << 3) + s;
    int l15  = lane & 15;
    float v;
    if (p < WE_HALVES) {
        int frag = p >> 9;
        int kt = frag >> 6, g = (frag >> 4) & 3, ntile = frag & 15;
        int k   = kt * 32 + kq;
        int row = g * 256 + ntile * 16 + l15;
        v = 0.0f;
        if (k < 256)      v = enc_Whh[row * 256 + k];
        else if (k < 272) v = enc_Wih[row * 16 + (k - 256)];
    } else {
        int q = p - WE_HALVES;
        int frag = q >> 9;
        int kt = frag >> 6, g = (frag >> 4) & 3, ntile = frag & 15;
        int k   = kt * 32 + kq;
        int row = g * 256 + ntile * 16 + l15;
        v = dec_Whh[row * 256 + k];
    }
    wf[p] = (_Float16)v;
}

__device__ __forceinline__ float sigm(float v) {
    return __builtin_amdgcn_rcpf(1.0f + __expf(-v));
}
__device__ __forceinline__ float tanh_f(float v) {
    return 1.0f - 2.0f * __builtin_amdgcn_rcpf(1.0f + __expf(2.0f * v));
}

// grid = 512 blocks = 2/CU (the new lever), 1024 threads = 16 waves. Wave w
// owns ntile w: unit-columns [w*16, w*16+16) for all 4 gates, ONE 16-row
// M-tile (MB=16). LDS 29.9 KB/block so two blocks co-reside; each block's
// barrier-drain and load-latency chains hide under the other block's compute
// (m114 wave-level overlap). __launch_bounds__(1024,8): 8 waves/SIMD -> VGPR
// cap 64 (the natural allocation every round), guaranteeing 2 blocks/CU.
__global__ __launch_bounds__(1024, 8) void seq2seq_mfma(
    const float* __restrict__ x,
    const _Float16* __restrict__ wf,
    const float* __restrict__ enc_b,
    const float* __restrict__ dec_b,
    const float* __restrict__ denseW,
    const float* __restrict__ denseb,
    float* __restrict__ out)
{
    __shared__ __align__(16) _Float16 hF[MB * KPAD];          // 9472 B
    __shared__ __align__(16) _Float16 xs[2][MB * CIN * 8];    // 8192 B
    __shared__ __align__(16) float    outS[MB * COUT * TOUT]; // 12288 B

    const int tid  = threadIdx.x;
    const int w    = tid >> 6;       // 0..15 = ntile
    const int lane = tid & 63;
    const int quad = lane >> 4;
    const int l15  = lane & 15;
    const int n0   = blockIdx.x * MB;

    float bE[4], bD[4];
    #pragma unroll
    for (int g = 0; g < 4; ++g) {
        int col = w * 16 + l15;
        bE[g] = enc_b[g * 256 + col];
        bD[g] = dec_b[g * 256 + col];
    }

    auto loadchunk = [&](int wd) {   // stage x[:, :, wd*8 .. wd*8+8) -> xs[wd&1]
        if (tid < MB * CIN) {
            int m = tid >> 4, c = tid & 15;
            const float* xp = x + (size_t)(n0 + m) * (CIN * TIN) + c * TIN + wd * 8;
            float4 v0 = *(const float4*)xp;
            float4 v1 = *(const float4*)(xp + 4);
            f16x8 hv = { (_Float16)v0.x, (_Float16)v0.y, (_Float16)v0.z, (_Float16)v0.w,
                         (_Float16)v1.x, (_Float16)v1.y, (_Float16)v1.z, (_Float16)v1.w };
            *(f16x8*)(&xs[wd & 1][m * (CIN * 8) + c * 8]) = hv;
        }
    };
    auto xcopy = [&](int t) {        // xs -> hF x-slot for step t
        if (tid < MB * CIN) {
            int m = tid >> 4, c = tid & 15;
            hF[m * KPAD + 256 + c] = xs[(t >> 3) & 1][m * (CIN * 8) + c * 8 + (t & 7)];
        }
    };

    for (int i = tid; i < MB * KPAD; i += 1024) hF[i] = (_Float16)0.0f;
    loadchunk(0);
    __syncthreads();
    xcopy(0);
    __syncthreads();

    f32x4 acc[4];           // [gate], single M-tile
    float cst[4];           // c-state, C-frag layout rows
    #pragma unroll
    for (int r = 0; r < 4; ++r) cst[r] = 0.0f;

    const f16x8* Ap0 = (const f16x8*)(hF + l15 * KPAD);
    const f16x8* WpE = (const f16x8*)wf + w * 64 + lane;
    const f16x8* WpD = (const f16x8*)(wf + WE_HALVES) + w * 64 + lane;

    auto gemm = [&](auto kt_tag, const f16x8* __restrict__ Wp, const float (&bias)[4]) {
        constexpr int KT = decltype(kt_tag)::val;
        #pragma unroll
        for (int g = 0; g < 4; ++g) {
            float b = bias[g];
            f32x4 bv = {b, b, b, b};
            acc[g] = bv;
        }
        #pragma unroll
        for (int kt = 0; kt < KT; ++kt) {
            f16x8 a0 = Ap0[kt * 4 + quad];
            #pragma unroll
            for (int g = 0; g < 4; ++g) {
                f16x8 bf = Wp[(kt * 4 + g) * 1024];   // frag (kt*64 + g*16 + w)
                acc[g] = __builtin_amdgcn_mfma_f32_16x16x32_f16(a0, bf, acc[g], 0, 0, 0);
            }
        }
    };

    auto pointwise = [&]() {
        int col = w * 16 + l15;
        #pragma unroll
        for (int r = 0; r < 4; ++r) {
            float iv = sigm(acc[0][r]);
            float fv = sigm(acc[1][r]);
            float gv = tanh_f(acc[2][r]);
            float ov = sigm(acc[3][r]);
            float cn = fmaf(fv, cst[r], iv * gv);
            cst[r] = cn;
            float hv = ov * tanh_f(cn);
            hF[(quad * 4 + r) * KPAD + col] = (_Float16)hv;
        }
    };

    // ================= encoder =================
    for (int t = 0; t < TIN; ++t) {
        gemm(KTag<KT_ENC>{}, WpE, bE);
        __syncthreads();              // all A-frag reads done
        pointwise();                  // write h_t
        if ((t & 7) == 0 && (t >> 3) + 1 < 6) loadchunk((t >> 3) + 1);
        if (t + 1 < TIN) xcopy(t + 1);
        __syncthreads();
    }

    // ================= decoder (c resets to 0) =================
    #pragma unroll
    for (int r = 0; r < 4; ++r) cst[r] = 0.0f;

    for (int t = 0; t < TOUT; ++t) {
        gemm(KTag<KT_DEC>{}, WpD, bD);
        __syncthreads();
        pointwise();
        __syncthreads();
        // dense epilogue -> LDS out buffer (threads 0..127). hF is read-only
        // until the next step's post-gemm barrier -> race-free.
        if (tid < MB * COUT) {
            int m = tid >> 3, o = tid & 7;
            const float* wr = denseW + (t * COUT + o) * HD;
            float s = denseb[t * COUT + o];
            #pragma unroll 4
            for (int j8 = 0; j8 < 32; ++j8) {
                f16x8 hv  = *(const f16x8*)(hF + m * KPAD + j8 * 8);
                float4 w0 = *(const float4*)(wr + j8 * 8);
                float4 w1 = *(const float4*)(wr + j8 * 8 + 4);
                s = fmaf((float)hv[0], w0.x, s);
                s = fmaf((float)hv[1], w0.y, s);
                s = fmaf((float)hv[2], w0.z, s);
                s = fmaf((float)hv[3], w0.w, s);
                s = fmaf((float)hv[4], w1.x, s);
                s = fmaf((float)hv[5], w1.y, s);
                s = fmaf((float)hv[6], w1.z, s);
                s = fmaf((float)hv[7], w1.w, s);
            }
            outS[m * (COUT * TOUT) + o * TOUT + t] = s;
        }
    }

    // ================= coalesced output flush =================
    __syncthreads();
    {
        const float4* src = (const float4*)outS;
        float4* dst = (float4*)(out + (size_t)n0 * (COUT * TOUT));
        for (int i = tid; i < MB * COUT * TOUT / 4; i += 1024)
            dst[i] = src[i];
    }
}

extern "C" void kernel_launch(void* const* d_in, const int* in_sizes, int n_in,
                              void* d_out, int out_size, void* d_ws, size_t ws_size,
                              hipStream_t stream) {
    const float* x       = (const float*)d_in[0];
    const float* enc_Wih = (const float*)d_in[1];
    const float* enc_Whh = (const float*)d_in[2];
    const float* enc_b   = (const float*)d_in[3];
    const float* dec_Whh = (const float*)d_in[4];
    const float* dec_b   = (const float*)d_in[5];
    const float* denseW  = (const float*)d_in[6];
    const float* denseb  = (const float*)d_in[7];
    float* out = (float*)d_out;
    _Float16* wf = (_Float16*)d_ws;   // 1.09 MB fragment-major fp16 weights

    prep_frags<<<(PREP_TOTAL + 255) / 256, 256, 0, stream>>>(enc_Wih, enc_Whh, dec_Whh, wf);
    seq2seq_mfma<<<8192 / MB, 1024, 0, stream>>>(x, wf, enc_b, dec_b, denseW, denseb, out);
}

// Round 7
// 2057.425 us; speedup vs baseline: 1.6427x; 1.6427x over previous
//
#include <hip/hip_runtime.h>

typedef __attribute__((ext_vector_type(8))) _Float16 f16x8;
typedef __attribute__((ext_vector_type(4))) _Float16 f16x4;
typedef __attribute__((ext_vector_type(4))) float    f32x4;

#define HD    256
#define CIN   16
#define TIN   48
#define TOUT  24
#define COUT  8
#define MB    64            // batch rows per block -> halves machine weight traffic
#define KPAD  296           // padded row stride (halves) for hF
#define KT_ENC 9            // K = 288 (h 256 | x 16 | pad 16)
#define KT_DEC 8            // K = 256
#define WE_HALVES (KT_ENC*4*16*512)   // 294912
#define WD_HALVES (KT_DEC*4*16*512)   // 262144
#define PREP_TOTAL (WE_HALVES + WD_HALVES)

template <int N> struct KTag { static constexpr int val = N; };

// Fragment-major fp16 weights: frag id = kt*64 + g*16 + ntile, each frag is
// 64 lanes x 8 halves with b_frag[lane][s] = W[k = kt*32 + (lane>>4)*8 + s]
//                                             [col = g*256 + ntile*16 + (lane&15)]
__global__ void prep_frags(const float* __restrict__ enc_Wih,
                           const float* __restrict__ enc_Whh,
                           const float* __restrict__ dec_Whh,
                           _Float16* __restrict__ wf)
{
    int p = blockIdx.x * blockDim.x + threadIdx.x;
    if (p >= PREP_TOTAL) return;
    int lane = (p >> 3) & 63;
    int s    = p & 7;
    int kq   = ((lane >> 4) << 3) + s;
    int l15  = lane & 15;
    float v;
    if (p < WE_HALVES) {
        int frag = p >> 9;
        int kt = frag >> 6, g = (frag >> 4) & 3, ntile = frag & 15;
        int k   = kt * 32 + kq;
        int row = g * 256 + ntile * 16 + l15;
        v = 0.0f;
        if (k < 256)      v = enc_Whh[row * 256 + k];
        else if (k < 272) v = enc_Wih[row * 16 + (k - 256)];
    } else {
        int q = p - WE_HALVES;
        int frag = q >> 9;
        int kt = frag >> 6, g = (frag >> 4) & 3, ntile = frag & 15;
        int k   = kt * 32 + kq;
        int row = g * 256 + ntile * 16 + l15;
        v = dec_Whh[row * 256 + k];
    }
    wf[p] = (_Float16)v;
}

__device__ __forceinline__ float sigm(float v) {
    return __builtin_amdgcn_rcpf(1.0f + __expf(-v));
}
__device__ __forceinline__ float tanh_f(float v) {
    return 1.0f - 2.0f * __builtin_amdgcn_rcpf(1.0f + __expf(2.0f * v));
}

// grid = 128 blocks, 1024 threads = 16 waves. Wave w owns ntile w across FOUR
// 16-row M-tiles (MB=64): each fetched weight frag feeds 4 MFMAs instead of 2
// -> machine-wide weight traffic halves vs MB=32. The r1 attempt of this
// config spilled: __launch_bounds__(1024,4) capped VGPRs at 64 while
// acc[4][4] alone needs 64. (1024,1) lifts the cap (grid gives 1 block/CU
// anyway, so nothing is lost); expect VGPR ~110, no scratch.
__global__ __launch_bounds__(1024, 1) void seq2seq_mfma(
    const float* __restrict__ x,
    const _Float16* __restrict__ wf,
    const float* __restrict__ enc_b,
    const float* __restrict__ dec_b,
    const float* __restrict__ denseW,
    const float* __restrict__ denseb,
    float* __restrict__ out)
{
    __shared__ __align__(16) _Float16 hF[MB * KPAD];           // 37888 B
    __shared__ __align__(16) _Float16 xs[2][MB * CIN * 4];     // 16384 B (4-step chunks)
    __shared__ __align__(16) float    outS4[MB * COUT * 4];    // 8192 B (4-step out staging)

    const int tid  = threadIdx.x;
    const int w    = tid >> 6;       // 0..15 = ntile
    const int lane = tid & 63;
    const int quad = lane >> 4;
    const int l15  = lane & 15;
    const int n0   = blockIdx.x * MB;

    float bE[4], bD[4];
    #pragma unroll
    for (int g = 0; g < 4; ++g) {
        int col = w * 16 + l15;
        bE[g] = enc_b[g * 256 + col];
        bD[g] = dec_b[g * 256 + col];
    }

    // stage x[:, :, wd*4 .. wd*4+4) -> xs[wd&1]; all 1024 threads, (m,c) pair each
    auto loadchunk = [&](int wd) {
        int m = tid >> 4, c = tid & 15;
        const float* xp = x + (size_t)(n0 + m) * (CIN * TIN) + c * TIN + wd * 4;
        float4 v = *(const float4*)xp;
        f16x4 hv = { (_Float16)v.x, (_Float16)v.y, (_Float16)v.z, (_Float16)v.w };
        *(f16x4*)(&xs[wd & 1][(m * CIN + c) * 4]) = hv;
    };
    auto xcopy = [&](int t) {        // xs -> hF x-slot for step t
        int m = tid >> 4, c = tid & 15;
        hF[m * KPAD + 256 + c] = xs[(t >> 2) & 1][(m * CIN + c) * 4 + (t & 3)];
    };

    for (int i = tid; i < MB * KPAD; i += 1024) hF[i] = (_Float16)0.0f;
    loadchunk(0);
    __syncthreads();
    xcopy(0);
    __syncthreads();

    f32x4 acc[4][4];        // [Mtile][gate]
    float cst[4][4];        // c-state, C-frag layout rows
    #pragma unroll
    for (int mt = 0; mt < 4; ++mt)
        #pragma unroll
        for (int r = 0; r < 4; ++r) cst[mt][r] = 0.0f;

    const f16x8* WpE = (const f16x8*)wf + w * 64 + lane;
    const f16x8* WpD = (const f16x8*)(wf + WE_HALVES) + w * 64 + lane;

    auto gemm = [&](auto kt_tag, const f16x8* __restrict__ Wp, const float (&bias)[4]) {
        constexpr int KT = decltype(kt_tag)::val;
        #pragma unroll
        for (int mt = 0; mt < 4; ++mt)
            #pragma unroll
            for (int g = 0; g < 4; ++g) {
                float b = bias[g];
                f32x4 bv = {b, b, b, b};
                acc[mt][g] = bv;
            }
        #pragma unroll
        for (int kt = 0; kt < KT; ++kt) {
            f16x8 bf[4];
            #pragma unroll
            for (int g = 0; g < 4; ++g)
                bf[g] = Wp[(kt * 4 + g) * 1024];   // frag (kt*64 + g*16 + w)
            #pragma unroll
            for (int mt = 0; mt < 4; ++mt) {
                f16x8 a = *(const f16x8*)(hF + (mt * 16 + l15) * KPAD + kt * 32 + quad * 8);
                #pragma unroll
                for (int g = 0; g < 4; ++g)
                    acc[mt][g] = __builtin_amdgcn_mfma_f32_16x16x32_f16(a, bf[g], acc[mt][g], 0, 0, 0);
            }
        }
    };

    auto pointwise = [&]() {
        int col = w * 16 + l15;
        #pragma unroll
        for (int mt = 0; mt < 4; ++mt)
            #pragma unroll
            for (int r = 0; r < 4; ++r) {
                float iv = sigm(acc[mt][0][r]);
                float fv = sigm(acc[mt][1][r]);
                float gv = tanh_f(acc[mt][2][r]);
                float ov = sigm(acc[mt][3][r]);
                float cn = fmaf(fv, cst[mt][r], iv * gv);
                cst[mt][r] = cn;
                float hv = ov * tanh_f(cn);
                hF[(mt * 16 + quad * 4 + r) * KPAD + col] = (_Float16)hv;
            }
    };

    // ================= encoder =================
    for (int t = 0; t < TIN; ++t) {
        gemm(KTag<KT_ENC>{}, WpE, bE);
        __syncthreads();              // all A-frag reads done
        pointwise();                  // write h_t
        if ((t & 3) == 0 && (t >> 2) + 1 < TIN / 4) loadchunk((t >> 2) + 1);
        if (t + 1 < TIN) xcopy(t + 1);
        __syncthreads();
    }

    // ================= decoder (c resets to 0) =================
    #pragma unroll
    for (int mt = 0; mt < 4; ++mt)
        #pragma unroll
        for (int r = 0; r < 4; ++r) cst[mt][r] = 0.0f;

    for (int t = 0; t < TOUT; ++t) {
        gemm(KTag<KT_DEC>{}, WpD, bD);
        __syncthreads();
        pointwise();
        __syncthreads();
        // dense epilogue (threads 0..511). hF is read-only until the next
        // step's post-gemm barrier -> race-free. outS4 slots are thread-
        // private: thread (m,o) writes its own 4 t-values and flushes them.
        if (tid < MB * COUT) {
            int m = tid >> 3, o = tid & 7;
            const float* wr = denseW + (t * COUT + o) * HD;
            float s = denseb[t * COUT + o];
            #pragma unroll 4
            for (int j8 = 0; j8 < 32; ++j8) {
                f16x8 hv  = *(const f16x8*)(hF + m * KPAD + j8 * 8);
                float4 w0 = *(const float4*)(wr + j8 * 8);
                float4 w1 = *(const float4*)(wr + j8 * 8 + 4);
                s = fmaf((float)hv[0], w0.x, s);
                s = fmaf((float)hv[1], w0.y, s);
                s = fmaf((float)hv[2], w0.z, s);
                s = fmaf((float)hv[3], w0.w, s);
                s = fmaf((float)hv[4], w1.x, s);
                s = fmaf((float)hv[5], w1.y, s);
                s = fmaf((float)hv[6], w1.z, s);
                s = fmaf((float)hv[7], w1.w, s);
            }
            outS4[(tid << 2) | (t & 3)] = s;
            if ((t & 3) == 3) {       // flush 4 finished t-values, 16B-aligned
                float4 v = *(const float4*)&outS4[tid << 2];
                *(float4*)(out + (size_t)(n0 + m) * (COUT * TOUT) + o * TOUT + (t - 3)) = v;
            }
        }
    }
}

extern "C" void kernel_launch(void* const* d_in, const int* in_sizes, int n_in,
                              void* d_out, int out_size, void* d_ws, size_t ws_size,
                              hipStream_t stream) {
    const float* x       = (const float*)d_in[0];
    const float* enc_Wih = (const float*)d_in[1];
    const float* enc_Whh = (const float*)d_in[2];
    const float* enc_b   = (const float*)d_in[3];
    const float* dec_Whh = (const float*)d_in[4];
    const float* dec_b   = (const float*)d_in[5];
    const float* denseW  = (const float*)d_in[6];
    const float* denseb  = (const float*)d_in[7];
    float* out = (float*)d_out;
    _Float16* wf = (_Float16*)d_ws;   // 1.09 MB fragment-major fp16 weights

    prep_frags<<<(PREP_TOTAL + 255) / 256, 256, 0, stream>>>(enc_Wih, enc_Whh, dec_Whh, wf);
    seq2seq_mfma<<<8192 / MB, 1024, 0, stream>>>(x, wf, enc_b, dec_b, denseW, denseb, out);
}

// Round 10
// 1435.026 us; speedup vs baseline: 2.3551x; 1.4337x over previous
//
#include <hip/hip_runtime.h>

typedef __attribute__((ext_vector_type(8))) _Float16 f16x8;
typedef __attribute__((ext_vector_type(4))) float    f32x4;

#define HD    256
#define CIN   16
#define TIN   48
#define TOUT  24
#define COUT  8
#define MB    32            // batch rows per block
#define KPAD  296           // padded row stride (halves) for hF
#define KT_ENC 9            // K = 288 (h 256 | x 16 | pad 16)
#define KT_DEC 8            // K = 256

template <int N> struct KTag { static constexpr int val = N; };

__device__ __forceinline__ float sigm(float v) {
    return __builtin_amdgcn_rcpf(1.0f + __expf(-v));
}
__device__ __forceinline__ float tanh_f(float v) {
    return 1.0f - 2.0f * __builtin_amdgcn_rcpf(1.0f + __expf(2.0f * v));
}

// grid = 256 blocks (1/CU), 1024 threads = 16 waves (4/SIMD). Wave w owns
// ntile w: unit-columns [w*16, w*16+16) for all 4 gates, both 16-row M-tiles.
// NO WORKSPACE: B-fragments are built on the fly from the ORIGINAL fp32
// weights in d_in (normal device memory). Every prior round streamed the
// repacked weights from d_ws, whose per-block WRITE signature (~1.09 MB = the
// weight set) and HBM re-fetch of an L2-sized working set indicate the
// workspace allocation bypasses normal L2 caching. Lane layout: for frag
// (kt,g,ntile=w), lane reads W[row = g*256 + w*16 + (lane&15)]
// [k = kt*32 + (lane>>4)*8 .. +8) as two float4s -> cvt to f16x8. Encoder
// kt=8: quads 0-1 from enc_Wih (16 cols), quads 2-3 zero (hF pad is zero).
__global__ __launch_bounds__(1024, 4) void seq2seq_mfma(
    const float* __restrict__ x,
    const float* __restrict__ enc_Wih,
    const float* __restrict__ enc_Whh,
    const float* __restrict__ enc_b,
    const float* __restrict__ dec_Whh,
    const float* __restrict__ dec_b,
    const float* __restrict__ denseW,
    const float* __restrict__ denseb,
    float* __restrict__ out)
{
    __shared__ __align__(16) _Float16 hF[MB * KPAD];          // 18.5 KB
    __shared__ __align__(16) _Float16 xs[2][MB * CIN * 8];    // 16 KB
    __shared__ __align__(16) float    outS[MB * COUT * TOUT]; // 24 KB

    const int tid  = threadIdx.x;
    const int w    = tid >> 6;       // 0..15 = ntile
    const int lane = tid & 63;
    const int quad = lane >> 4;
    const int l15  = lane & 15;
    const int n0   = blockIdx.x * MB;

    float bE[4], bD[4];
    int offhh[4], offih[4];          // per-gate element offsets for this lane
    #pragma unroll
    for (int g = 0; g < 4; ++g) {
        int col = w * 16 + l15;      // output unit this lane covers
        int row = g * 256 + col;     // row in the (4H, K) weight matrices
        bE[g] = enc_b[row];
        bD[g] = dec_b[row];
        offhh[g] = row * 256 + quad * 8;
        offih[g] = row * 16 + quad * 8;   // valid only for quad < 2
    }

    auto loadchunk = [&](int wd) {   // stage x[:, :, wd*8 .. wd*8+8) -> xs[wd&1]
        if (tid < 512) {
            int m = tid >> 4, c = tid & 15;
            const float* xp = x + (size_t)(n0 + m) * (CIN * TIN) + c * TIN + wd * 8;
            float4 v0 = *(const float4*)xp;
            float4 v1 = *(const float4*)(xp + 4);
            f16x8 hv = { (_Float16)v0.x, (_Float16)v0.y, (_Float16)v0.z, (_Float16)v0.w,
                         (_Float16)v1.x, (_Float16)v1.y, (_Float16)v1.z, (_Float16)v1.w };
            *(f16x8*)(&xs[wd & 1][m * (CIN * 8) + c * 8]) = hv;
        }
    };
    auto xcopy = [&](int t) {        // xs -> hF x-slot for step t
        if (tid < 512) {
            int m = tid >> 4, c = tid & 15;
            hF[m * KPAD + 256 + c] = xs[(t >> 3) & 1][m * (CIN * 8) + c * 8 + (t & 7)];
        }
    };

    for (int i = tid; i < MB * KPAD; i += 1024) hF[i] = (_Float16)0.0f;
    loadchunk(0);
    __syncthreads();
    xcopy(0);
    __syncthreads();

    f32x4 acc[2][4];        // [Mtile][gate]
    float cst[2][4];        // c-state, C-frag layout rows
    #pragma unroll
    for (int mt = 0; mt < 2; ++mt)
        #pragma unroll
        for (int r = 0; r < 4; ++r) cst[mt][r] = 0.0f;

    const f16x8* Ap0 = (const f16x8*)(hF + l15 * KPAD);          // Mtile 0
    const f16x8* Ap1 = (const f16x8*)(hF + (16 + l15) * KPAD);   // Mtile 1

    auto gemm = [&](auto kt_tag, const float* __restrict__ Whh, const float (&bias)[4]) {
        constexpr int KT = decltype(kt_tag)::val;   // 9 = encoder, 8 = decoder
        #pragma unroll
        for (int mt = 0; mt < 2; ++mt)
            #pragma unroll
            for (int g = 0; g < 4; ++g) {
                float b = bias[g];
                f32x4 bv = {b, b, b, b};
                acc[mt][g] = bv;
            }
        #pragma unroll
        for (int kt = 0; kt < KT; ++kt) {
            f16x8 a0 = Ap0[kt * 4 + quad];
            f16x8 a1 = Ap1[kt * 4 + quad];
            #pragma unroll
            for (int g = 0; g < 4; ++g) {
                f16x8 bf;
                if (kt < 8) {
                    const float* p = Whh + offhh[g] + kt * 32;
                    float4 v0 = *(const float4*)p;
                    float4 v1 = *(const float4*)(p + 4);
                    bf = f16x8{ (_Float16)v0.x, (_Float16)v0.y, (_Float16)v0.z, (_Float16)v0.w,
                                (_Float16)v1.x, (_Float16)v1.y, (_Float16)v1.z, (_Float16)v1.w };
                } else {            // encoder x-columns: k = 256..287
                    bf = f16x8{ (_Float16)0.0f, (_Float16)0.0f, (_Float16)0.0f, (_Float16)0.0f,
                                (_Float16)0.0f, (_Float16)0.0f, (_Float16)0.0f, (_Float16)0.0f };
                    if (quad < 2) { // k=256..271 -> Wih cols 0..15; quads 2,3 pad
                        const float* p = enc_Wih + offih[g];
                        float4 v0 = *(const float4*)p;
                        float4 v1 = *(const float4*)(p + 4);
                        bf = f16x8{ (_Float16)v0.x, (_Float16)v0.y, (_Float16)v0.z, (_Float16)v0.w,
                                    (_Float16)v1.x, (_Float16)v1.y, (_Float16)v1.z, (_Float16)v1.w };
                    }
                }
                acc[0][g] = __builtin_amdgcn_mfma_f32_16x16x32_f16(a0, bf, acc[0][g], 0, 0, 0);
                acc[1][g] = __builtin_amdgcn_mfma_f32_16x16x32_f16(a1, bf, acc[1][g], 0, 0, 0);
            }
        }
    };

    auto pointwise = [&]() {
        int col = w * 16 + l15;
        #pragma unroll
        for (int mt = 0; mt < 2; ++mt)
            #pragma unroll
            for (int r = 0; r < 4; ++r) {
                float iv = sigm(acc[mt][0][r]);
                float fv = sigm(acc[mt][1][r]);
                float gv = tanh_f(acc[mt][2][r]);
                float ov = sigm(acc[mt][3][r]);
                float cn = fmaf(fv, cst[mt][r], iv * gv);
                cst[mt][r] = cn;
                float hv = ov * tanh_f(cn);
                hF[(mt * 16 + quad * 4 + r) * KPAD + col] = (_Float16)hv;
            }
    };

    // ================= encoder =================
    for (int t = 0; t < TIN; ++t) {
        gemm(KTag<KT_ENC>{}, enc_Whh, bE);
        __syncthreads();              // all A-frag reads done
        pointwise();                  // write h_t
        if ((t & 7) == 0 && (t >> 3) + 1 < 6) loadchunk((t >> 3) + 1);
        if (t + 1 < TIN) xcopy(t + 1);
        __syncthreads();
    }

    // ================= decoder (c resets to 0) =================
    #pragma unroll
    for (int mt = 0; mt < 2; ++mt)
        #pragma unroll
        for (int r = 0; r < 4; ++r) cst[mt][r] = 0.0f;

    for (int t = 0; t < TOUT; ++t) {
        gemm(KTag<KT_DEC>{}, dec_Whh, bD);
        __syncthreads();
        pointwise();
        __syncthreads();
        // dense epilogue -> LDS out buffer (threads 0..255). hF is read-only
        // until the next step's post-gemm barrier -> race-free.
        if (tid < MB * COUT) {
            int m = tid >> 3, o = tid & 7;
            const float* wr = denseW + (t * COUT + o) * HD;
            float s = denseb[t * COUT + o];
            #pragma unroll 4
            for (int j8 = 0; j8 < 32; ++j8) {
                f16x8 hv  = *(const f16x8*)(hF + m * KPAD + j8 * 8);
                float4 w0 = *(const float4*)(wr + j8 * 8);
                float4 w1 = *(const float4*)(wr + j8 * 8 + 4);
                s = fmaf((float)hv[0], w0.x, s);
                s = fmaf((float)hv[1], w0.y, s);
                s = fmaf((float)hv[2], w0.z, s);
                s = fmaf((float)hv[3], w0.w, s);
                s = fmaf((float)hv[4], w1.x, s);
                s = fmaf((float)hv[5], w1.y, s);
                s = fmaf((float)hv[6], w1.z, s);
                s = fmaf((float)hv[7], w1.w, s);
            }
            outS[m * (COUT * TOUT) + o * TOUT + t] = s;
        }
    }

    // ================= coalesced output flush =================
    __syncthreads();
    {
        const float4* src = (const float4*)outS;
        float4* dst = (float4*)(out + (size_t)n0 * (COUT * TOUT));
        for (int i = tid; i < MB * COUT * TOUT / 4; i += 1024)
            dst[i] = src[i];
    }
}

extern "C" void kernel_launch(void* const* d_in, const int* in_sizes, int n_in,
                              void* d_out, int out_size, void* d_ws, size_t ws_size,
                              hipStream_t stream) {
    const float* x       = (const float*)d_in[0];
    const float* enc_Wih = (const float*)d_in[1];
    const float* enc_Whh = (const float*)d_in[2];
    const float* enc_b   = (const float*)d_in[3];
    const float* dec_Whh = (const float*)d_in[4];
    const float* dec_b   = (const float*)d_in[5];
    const float* denseW  = (const float*)d_in[6];
    const float* denseb  = (const float*)d_in[7];
    float* out = (float*)d_out;
    (void)d_ws; (void)ws_size;       // workspace intentionally unused

    seq2seq_mfma<<<8192 / MB, 1024, 0, stream>>>(
        x, enc_Wih, enc_Whh, enc_b, dec_Whh, dec_b, denseW, denseb, out);
}

// Round 11
// 1138.905 us; speedup vs baseline: 2.9674x; 1.2600x over previous
//
#include <hip/hip_runtime.h>

typedef __attribute__((ext_vector_type(8))) _Float16 f16x8;
typedef __attribute__((ext_vector_type(4))) float    f32x4;

#define HD    256
#define CIN   16
#define TIN   48
#define TOUT  24
#define COUT  8
#define MB    32            // batch rows per block
#define KPAD  296           // padded row stride (halves) for hF
#define KT_ENC 9            // K = 288 (h 256 | x 16 | pad 16)
#define KT_DEC 8            // K = 256
#define WE_HALVES (KT_ENC*4*16*512)   // 294912
#define WD_HALVES (KT_DEC*4*16*512)   // 262144
#define PREP_TOTAL (WE_HALVES + WD_HALVES)

template <int N> struct KTag { static constexpr int val = N; };

// Fragment-major fp16 weights: frag id = kt*64 + g*16 + ntile, each frag is
// 64 lanes x 8 halves with b_frag[lane][s] = W[k = kt*32 + (lane>>4)*8 + s]
//                                             [col = g*256 + ntile*16 + (lane&15)]
__global__ void prep_frags(const float* __restrict__ enc_Wih,
                           const float* __restrict__ enc_Whh,
                           const float* __restrict__ dec_Whh,
                           _Float16* __restrict__ wf)
{
    int p = blockIdx.x * blockDim.x + threadIdx.x;
    if (p >= PREP_TOTAL) return;
    int lane = (p >> 3) & 63;
    int s    = p & 7;
    int kq   = ((lane >> 4) << 3) + s;
    int l15  = lane & 15;
    float v;
    if (p < WE_HALVES) {
        int frag = p >> 9;
        int kt = frag >> 6, g = (frag >> 4) & 3, ntile = frag & 15;
        int k   = kt * 32 + kq;
        int row = g * 256 + ntile * 16 + l15;
        v = 0.0f;
        if (k < 256)      v = enc_Whh[row * 256 + k];
        else if (k < 272) v = enc_Wih[row * 16 + (k - 256)];
    } else {
        int q = p - WE_HALVES;
        int frag = q >> 9;
        int kt = frag >> 6, g = (frag >> 4) & 3, ntile = frag & 15;
        int k   = kt * 32 + kq;
        int row = g * 256 + ntile * 16 + l15;
        v = dec_Whh[row * 256 + k];
    }
    wf[p] = (_Float16)v;
}

__device__ __forceinline__ float sigm(float v) {
    return __builtin_amdgcn_rcpf(1.0f + __expf(-v));
}
__device__ __forceinline__ float tanh_f(float v) {
    return 1.0f - 2.0f * __builtin_amdgcn_rcpf(1.0f + __expf(2.0f * v));
}

// Async global->LDS stage of one 1KB weight fragment: 64 lanes x 16B.
// Global src is per-lane; LDS dest = wave-uniform base + lane*16 (matches the
// fragment layout exactly, so the read-back is lane-local and conflict-free).
__device__ __forceinline__ void gld_lds16(const _Float16* g, _Float16* l) {
    __builtin_amdgcn_global_load_lds(
        (const __attribute__((address_space(1))) void*)g,
        (__attribute__((address_space(3))) void*)l, 16, 0, 0);
}

// grid = 256 blocks (1/CU), 1024 threads = 16 waves (4/SIMD). Wave w owns
// ntile w: unit-columns [w*16,w*16+16) for all 4 gates, both 16-row M-tiles.
// WEIGHTS NEVER TOUCH VGPRs: each wave streams its 36 (enc) / 32 (dec) 1KB
// frags through a private 8KB LDS double buffer via global_load_lds with
// counted vmcnt(4) (never 0 mid-loop). The measured wall is inflight-limited
// L2-miss service (~2KB inflight/CU at ~550cy L3 latency = ~4 B/cy/CU); this
// pipeline holds up to ~128KB/CU inflight. Counted waits are robust to
// compiler-inserted junk VMEM at any interleave point (in-order vmcnt
// retirement). LDS total 154112 B <= 163840.
__global__ __launch_bounds__(1024, 1) void seq2seq_mfma(
    const float* __restrict__ x,
    const _Float16* __restrict__ wf,
    const float* __restrict__ enc_b,
    const float* __restrict__ dec_b,
    const float* __restrict__ denseW,
    const float* __restrict__ denseb,
    float* __restrict__ out)
{
    __shared__ __align__(16) _Float16 hF[MB * KPAD];          // 18944 B
    __shared__ __align__(16) _Float16 Wlds[16][2][4][512];    // 131072 B
    __shared__ __align__(16) float    outS4[MB * COUT * 4];   // 4096 B

    const int tid  = threadIdx.x;
    const int w    = tid >> 6;       // 0..15 = ntile
    const int lane = tid & 63;
    const int quad = lane >> 4;
    const int l15  = lane & 15;
    const int n0   = blockIdx.x * MB;

    float bE[4], bD[4];
    #pragma unroll
    for (int g = 0; g < 4; ++g) {
        int col = w * 16 + l15;
        bE[g] = enc_b[g * 256 + col];
        bD[g] = dec_b[g * 256 + col];
    }

    for (int i = tid; i < MB * KPAD; i += 1024) hF[i] = (_Float16)0.0f;
    __syncthreads();
    if (tid < 512) {                 // x for step 0
        int m = tid >> 4, c = tid & 15;
        hF[m * KPAD + 256 + c] = (_Float16)x[(size_t)(n0 + m) * (CIN * TIN) + c * TIN];
    }
    __syncthreads();

    f32x4 acc[2][4];        // [Mtile][gate]
    float cst[2][4];        // c-state, C-frag layout rows
    #pragma unroll
    for (int mt = 0; mt < 2; ++mt)
        #pragma unroll
        for (int r = 0; r < 4; ++r) cst[mt][r] = 0.0f;

    const f16x8* Ap0 = (const f16x8*)(hF + l15 * KPAD);          // Mtile 0
    const f16x8* Ap1 = (const f16x8*)(hF + (16 + l15) * KPAD);   // Mtile 1

    // stage kt-group (4 frags) into this wave's LDS buffer `buf`
    auto stage = [&](int buf, int kt, const _Float16* __restrict__ Wbase) {
        #pragma unroll
        for (int g = 0; g < 4; ++g) {
            const _Float16* gp = Wbase + (size_t)(kt * 64 + g * 16 + w) * 512 + lane * 8;
            gld_lds16(gp, &Wlds[w][buf][g][0]);
        }
    };

    auto gemm = [&](auto kt_tag, const _Float16* __restrict__ Wbase, const float (&bias)[4]) {
        constexpr int KT = decltype(kt_tag)::val;
        #pragma unroll
        for (int mt = 0; mt < 2; ++mt)
            #pragma unroll
            for (int g = 0; g < 4; ++g) {
                float b = bias[g];
                f32x4 bv = {b, b, b, b};
                acc[mt][g] = bv;
            }
        stage(0, 0, Wbase);
        #pragma unroll
        for (int kt = 0; kt < KT; ++kt) {
            if (kt + 1 < KT) {
                stage((kt + 1) & 1, kt + 1, Wbase);
                // <=4 newest outstanding => group kt fully landed in LDS
                asm volatile("s_waitcnt vmcnt(4)" ::: "memory");
            } else {
                asm volatile("s_waitcnt vmcnt(0)" ::: "memory");
            }
            __builtin_amdgcn_sched_barrier(0);
            f16x8 a0 = Ap0[kt * 4 + quad];
            f16x8 a1 = Ap1[kt * 4 + quad];
            const int b = kt & 1;
            #pragma unroll
            for (int g = 0; g < 4; ++g) {
                f16x8 bf = *(const f16x8*)&Wlds[w][b][g][lane * 8];
                acc[0][g] = __builtin_amdgcn_mfma_f32_16x16x32_f16(a0, bf, acc[0][g], 0, 0, 0);
                acc[1][g] = __builtin_amdgcn_mfma_f32_16x16x32_f16(a1, bf, acc[1][g], 0, 0, 0);
            }
        }
    };

    auto pointwise = [&]() {
        int col = w * 16 + l15;
        #pragma unroll
        for (int mt = 0; mt < 2; ++mt)
            #pragma unroll
            for (int r = 0; r < 4; ++r) {
                float iv = sigm(acc[mt][0][r]);
                float fv = sigm(acc[mt][1][r]);
                float gv = tanh_f(acc[mt][2][r]);
                float ov = sigm(acc[mt][3][r]);
                float cn = fmaf(fv, cst[mt][r], iv * gv);
                cst[mt][r] = cn;
                float hv = ov * tanh_f(cn);
                hF[(mt * 16 + quad * 4 + r) * KPAD + col] = (_Float16)hv;
            }
    };

    // ================= encoder =================
    for (int t = 0; t < TIN; ++t) {
        float xv = 0.0f;
        const bool xl = (tid < 512) && (t + 1 < TIN);
        if (xl)          // issued BEFORE the pipeline loads -> always older
            xv = x[(size_t)(n0 + (tid >> 4)) * (CIN * TIN) + (tid & 15) * TIN + (t + 1)];
        gemm(KTag<KT_ENC>{}, wf, bE);
        __syncthreads();              // all A-frag reads done
        pointwise();                  // write h_t
        if (xl) hF[(tid >> 4) * KPAD + 256 + (tid & 15)] = (_Float16)xv;
        __syncthreads();
    }

    // ================= decoder (c resets to 0) =================
    #pragma unroll
    for (int mt = 0; mt < 2; ++mt)
        #pragma unroll
        for (int r = 0; r < 4; ++r) cst[mt][r] = 0.0f;

    for (int t = 0; t < TOUT; ++t) {
        gemm(KTag<KT_DEC>{}, wf + WE_HALVES, bD);
        __syncthreads();
        pointwise();
        __syncthreads();
        // dense epilogue (threads 0..255). hF is read-only until the next
        // step's post-gemm barrier -> race-free. outS4 slots thread-private.
        if (tid < MB * COUT) {
            int m = tid >> 3, o = tid & 7;
            const float* wr = denseW + (t * COUT + o) * HD;
            float s = denseb[t * COUT + o];
            #pragma unroll 4
            for (int j8 = 0; j8 < 32; ++j8) {
                f16x8 hv  = *(const f16x8*)(hF + m * KPAD + j8 * 8);
                float4 w0 = *(const float4*)(wr + j8 * 8);
                float4 w1 = *(const float4*)(wr + j8 * 8 + 4);
                s = fmaf((float)hv[0], w0.x, s);
                s = fmaf((float)hv[1], w0.y, s);
                s = fmaf((float)hv[2], w0.z, s);
                s = fmaf((float)hv[3], w0.w, s);
                s = fmaf((float)hv[4], w1.x, s);
                s = fmaf((float)hv[5], w1.y, s);
                s = fmaf((float)hv[6], w1.z, s);
                s = fmaf((float)hv[7], w1.w, s);
            }
            outS4[(tid << 2) | (t & 3)] = s;
            if ((t & 3) == 3) {       // flush 4 finished t-values, 16B-aligned
                float4 v = *(const float4*)&outS4[tid << 2];
                *(float4*)(out + (size_t)(n0 + m) * (COUT * TOUT) + o * TOUT + (t - 3)) = v;
            }
        }
    }
}

extern "C" void kernel_launch(void* const* d_in, const int* in_sizes, int n_in,
                              void* d_out, int out_size, void* d_ws, size_t ws_size,
                              hipStream_t stream) {
    const float* x       = (const float*)d_in[0];
    const float* enc_Wih = (const float*)d_in[1];
    const float* enc_Whh = (const float*)d_in[2];
    const float* enc_b   = (const float*)d_in[3];
    const float* dec_Whh = (const float*)d_in[4];
    const float* dec_b   = (const float*)d_in[5];
    const float* denseW  = (const float*)d_in[6];
    const float* denseb  = (const float*)d_in[7];
    float* out = (float*)d_out;
    _Float16* wf = (_Float16*)d_ws;   // 1.09 MB fragment-major fp16 weights

    prep_frags<<<(PREP_TOTAL + 255) / 256, 256, 0, stream>>>(enc_Wih, enc_Whh, dec_Whh, wf);
    seq2seq_mfma<<<8192 / MB, 1024, 0, stream>>>(x, wf, enc_b, dec_b, denseW, denseb, out);
}

// Round 12
// 1125.373 us; speedup vs baseline: 3.0031x; 1.0120x over previous
//
#include <hip/hip_runtime.h>

typedef __attribute__((ext_vector_type(8))) _Float16 f16x8;
typedef __attribute__((ext_vector_type(4))) float    f32x4;

#define HD    256
#define CIN   16
#define TIN   48
#define TOUT  24
#define COUT  8
#define MB    32            // batch rows per block
#define KPAD  296           // padded row stride (halves) for hF
#define KT_ENC 9            // K = 288 (h 256 | x 16 | pad 16)
#define KT_DEC 8            // K = 256
#define WE_HALVES (KT_ENC*4*16*512)   // 294912
#define WD_HALVES (KT_DEC*4*16*512)   // 262144
#define PREP_TOTAL (WE_HALVES + WD_HALVES)

template <int N> struct KTag { static constexpr int val = N; };

// Fragment-major fp16 weights: frag id = kt*64 + g*16 + ntile, each frag is
// 64 lanes x 8 halves with b_frag[lane][s] = W[k = kt*32 + (lane>>4)*8 + s]
//                                             [col = g*256 + ntile*16 + (lane&15)]
__global__ void prep_frags(const float* __restrict__ enc_Wih,
                           const float* __restrict__ enc_Whh,
                           const float* __restrict__ dec_Whh,
                           _Float16* __restrict__ wf)
{
    int p = blockIdx.x * blockDim.x + threadIdx.x;
    if (p >= PREP_TOTAL) return;
    int lane = (p >> 3) & 63;
    int s    = p & 7;
    int kq   = ((lane >> 4) << 3) + s;
    int l15  = lane & 15;
    float v;
    if (p < WE_HALVES) {
        int frag = p >> 9;
        int kt = frag >> 6, g = (frag >> 4) & 3, ntile = frag & 15;
        int k   = kt * 32 + kq;
        int row = g * 256 + ntile * 16 + l15;
        v = 0.0f;
        if (k < 256)      v = enc_Whh[row * 256 + k];
        else if (k < 272) v = enc_Wih[row * 16 + (k - 256)];
    } else {
        int q = p - WE_HALVES;
        int frag = q >> 9;
        int kt = frag >> 6, g = (frag >> 4) & 3, ntile = frag & 15;
        int k   = kt * 32 + kq;
        int row = g * 256 + ntile * 16 + l15;
        v = dec_Whh[row * 256 + k];
    }
    wf[p] = (_Float16)v;
}

__device__ __forceinline__ float sigm(float v) {
    return __builtin_amdgcn_rcpf(1.0f + __expf(-v));
}
__device__ __forceinline__ float tanh_f(float v) {
    return 1.0f - 2.0f * __builtin_amdgcn_rcpf(1.0f + __expf(2.0f * v));
}

// Async global->LDS stage of one 1KB weight fragment: 64 lanes x 16B.
__device__ __forceinline__ void gld_lds16(const _Float16* g, _Float16* l) {
    __builtin_amdgcn_global_load_lds(
        (const __attribute__((address_space(1))) void*)g,
        (__attribute__((address_space(3))) void*)l, 16, 0, 0);
}

// grid = 256 blocks (1/CU), 1024 threads = 16 waves (4/SIMD). Wave w owns
// ntile w. Weights stream global->LDS via an 8-slot x 1KB PER-FRAG ring per
// wave (vs r11's 2x4KB group double-buffer): stage frag f+7, wait vmcnt(7),
// consume frag f. Issue-to-use = 7 iterations (~300+cy) -> L2 latency fully
// covered; counted waits never drain mid-loop (tail 6..0). Slot-reuse safe:
// stage(f+7) targets frag f-1's slot, whose ds_read completed (lgkmcnt
// before its MFMA) a full iteration + ~200cy global latency earlier. Junk
// VMEM (x preload / epilogue) is strictly older than pipeline loads ->
// counted waits stay conservative. LDS 154112 B (same as r11).
__global__ __launch_bounds__(1024, 1) void seq2seq_mfma(
    const float* __restrict__ x,
    const _Float16* __restrict__ wf,
    const float* __restrict__ enc_b,
    const float* __restrict__ dec_b,
    const float* __restrict__ denseW,
    const float* __restrict__ denseb,
    float* __restrict__ out)
{
    __shared__ __align__(16) _Float16 hF[MB * KPAD];          // 18944 B
    __shared__ __align__(16) _Float16 Wlds[16][8][512];       // 131072 B
    __shared__ __align__(16) float    outS4[MB * COUT * 4];   // 4096 B

    const int tid  = threadIdx.x;
    const int w    = tid >> 6;       // 0..15 = ntile
    const int lane = tid & 63;
    const int quad = lane >> 4;
    const int l15  = lane & 15;
    const int n0   = blockIdx.x * MB;

    float bE[4], bD[4];
    #pragma unroll
    for (int g = 0; g < 4; ++g) {
        int col = w * 16 + l15;
        bE[g] = enc_b[g * 256 + col];
        bD[g] = dec_b[g * 256 + col];
    }

    for (int i = tid; i < MB * KPAD; i += 1024) hF[i] = (_Float16)0.0f;
    __syncthreads();
    if (tid < 512) {                 // x for step 0
        int m = tid >> 4, c = tid & 15;
        hF[m * KPAD + 256 + c] = (_Float16)x[(size_t)(n0 + m) * (CIN * TIN) + c * TIN];
    }
    __syncthreads();

    f32x4 acc[2][4];        // [Mtile][gate]
    float cst[2][4];        // c-state, C-frag layout rows
    #pragma unroll
    for (int mt = 0; mt < 2; ++mt)
        #pragma unroll
        for (int r = 0; r < 4; ++r) cst[mt][r] = 0.0f;

    const f16x8* Ap0 = (const f16x8*)(hF + l15 * KPAD);          // Mtile 0
    const f16x8* Ap1 = (const f16x8*)(hF + (16 + l15) * KPAD);   // Mtile 1

    // stage frag f (kt = f>>2, gate = f&3) into ring slot f&7
    auto stagef = [&](int f, const _Float16* __restrict__ Wbase) {
        int kt = f >> 2, g = f & 3;
        const _Float16* gp = Wbase + (size_t)(kt * 64 + g * 16 + w) * 512 + lane * 8;
        gld_lds16(gp, &Wlds[w][f & 7][0]);
    };

    auto gemm = [&](auto kt_tag, const _Float16* __restrict__ Wbase, const float (&bias)[4]) {
        constexpr int KT = decltype(kt_tag)::val;
        constexpr int NF = KT * 4;
        #pragma unroll
        for (int mt = 0; mt < 2; ++mt)
            #pragma unroll
            for (int g = 0; g < 4; ++g) {
                float b = bias[g];
                f32x4 bv = {b, b, b, b};
                acc[mt][g] = bv;
            }
        f16x8 a0, a1;
        auto body = [&](int f) {
            int kt = f >> 2, g = f & 3;
            if ((f & 3) == 0) {           // folds: f is compile-time constant
                a0 = Ap0[kt * 4 + quad];
                a1 = Ap1[kt * 4 + quad];
            }
            f16x8 bf = *(const f16x8*)&Wlds[w][f & 7][lane * 8];
            acc[0][g] = __builtin_amdgcn_mfma_f32_16x16x32_f16(a0, bf, acc[0][g], 0, 0, 0);
            acc[1][g] = __builtin_amdgcn_mfma_f32_16x16x32_f16(a1, bf, acc[1][g], 0, 0, 0);
        };
        #pragma unroll
        for (int f = 0; f < 7; ++f) stagef(f, Wbase);   // fill ring
        #pragma unroll
        for (int f = 0; f < NF - 7; ++f) {
            stagef(f + 7, Wbase);
            asm volatile("s_waitcnt vmcnt(7)" ::: "memory");
            __builtin_amdgcn_sched_barrier(0);
            body(f);
        }
        // tail: frags NF-7 .. NF-1, waits 6..0 (full drain at the end)
        asm volatile("s_waitcnt vmcnt(6)" ::: "memory"); __builtin_amdgcn_sched_barrier(0); body(NF - 7);
        asm volatile("s_waitcnt vmcnt(5)" ::: "memory"); __builtin_amdgcn_sched_barrier(0); body(NF - 6);
        asm volatile("s_waitcnt vmcnt(4)" ::: "memory"); __builtin_amdgcn_sched_barrier(0); body(NF - 5);
        asm volatile("s_waitcnt vmcnt(3)" ::: "memory"); __builtin_amdgcn_sched_barrier(0); body(NF - 4);
        asm volatile("s_waitcnt vmcnt(2)" ::: "memory"); __builtin_amdgcn_sched_barrier(0); body(NF - 3);
        asm volatile("s_waitcnt vmcnt(1)" ::: "memory"); __builtin_amdgcn_sched_barrier(0); body(NF - 2);
        asm volatile("s_waitcnt vmcnt(0)" ::: "memory"); __builtin_amdgcn_sched_barrier(0); body(NF - 1);
    };

    auto pointwise = [&]() {
        int col = w * 16 + l15;
        #pragma unroll
        for (int mt = 0; mt < 2; ++mt)
            #pragma unroll
            for (int r = 0; r < 4; ++r) {
                float iv = sigm(acc[mt][0][r]);
                float fv = sigm(acc[mt][1][r]);
                float gv = tanh_f(acc[mt][2][r]);
                float ov = sigm(acc[mt][3][r]);
                float cn = fmaf(fv, cst[mt][r], iv * gv);
                cst[mt][r] = cn;
                float hv = ov * tanh_f(cn);
                hF[(mt * 16 + quad * 4 + r) * KPAD + col] = (_Float16)hv;
            }
    };

    // ================= encoder =================
    for (int t = 0; t < TIN; ++t) {
        float xv = 0.0f;
        const bool xl = (tid < 512) && (t + 1 < TIN);
        if (xl)          // issued BEFORE the pipeline loads -> always older
            xv = x[(size_t)(n0 + (tid >> 4)) * (CIN * TIN) + (tid & 15) * TIN + (t + 1)];
        gemm(KTag<KT_ENC>{}, wf, bE);
        __syncthreads();              // all A-frag reads done
        pointwise();                  // write h_t
        if (xl) hF[(tid >> 4) * KPAD + 256 + (tid & 15)] = (_Float16)xv;
        __syncthreads();
    }

    // ================= decoder (c resets to 0) =================
    #pragma unroll
    for (int mt = 0; mt < 2; ++mt)
        #pragma unroll
        for (int r = 0; r < 4; ++r) cst[mt][r] = 0.0f;

    for (int t = 0; t < TOUT; ++t) {
        gemm(KTag<KT_DEC>{}, wf + WE_HALVES, bD);
        __syncthreads();
        pointwise();
        __syncthreads();
        // dense epilogue (threads 0..255). hF is read-only until the next
        // step's post-gemm barrier -> race-free. outS4 slots thread-private.
        if (tid < MB * COUT) {
            int m = tid >> 3, o = tid & 7;
            const float* wr = denseW + (t * COUT + o) * HD;
            float s = denseb[t * COUT + o];
            #pragma unroll 4
            for (int j8 = 0; j8 < 32; ++j8) {
                f16x8 hv  = *(const f16x8*)(hF + m * KPAD + j8 * 8);
                float4 w0 = *(const float4*)(wr + j8 * 8);
                float4 w1 = *(const float4*)(wr + j8 * 8 + 4);
                s = fmaf((float)hv[0], w0.x, s);
                s = fmaf((float)hv[1], w0.y, s);
                s = fmaf((float)hv[2], w0.z, s);
                s = fmaf((float)hv[3], w0.w, s);
                s = fmaf((float)hv[4], w1.x, s);
                s = fmaf((float)hv[5], w1.y, s);
                s = fmaf((float)hv[6], w1.z, s);
                s = fmaf((float)hv[7], w1.w, s);
            }
            outS4[(tid << 2) | (t & 3)] = s;
            if ((t & 3) == 3) {       // flush 4 finished t-values, 16B-aligned
                float4 v = *(const float4*)&outS4[tid << 2];
                *(float4*)(out + (size_t)(n0 + m) * (COUT * TOUT) + o * TOUT + (t - 3)) = v;
            }
        }
    }
}

extern "C" void kernel_launch(void* const* d_in, const int* in_sizes, int n_in,
                              void* d_out, int out_size, void* d_ws, size_t ws_size,
                              hipStream_t stream) {
    const float* x       = (const float*)d_in[0];
    const float* enc_Wih = (const float*)d_in[1];
    const float* enc_Whh = (const float*)d_in[2];
    const float* enc_b   = (const float*)d_in[3];
    const float* dec_Whh = (const float*)d_in[4];
    const float* dec_b   = (const float*)d_in[5];
    const float* denseW  = (const float*)d_in[6];
    const float* denseb  = (const float*)d_in[7];
    float* out = (float*)d_out;
    _Float16* wf = (_Float16*)d_ws;   // 1.09 MB fragment-major fp16 weights

    prep_frags<<<(PREP_TOTAL + 255) / 256, 256, 0, stream>>>(enc_Wih, enc_Whh, dec_Whh, wf);
    seq2seq_mfma<<<8192 / MB, 1024, 0, stream>>>(x, wf, enc_b, dec_b, denseW, denseb, out);
}